// Round 17
// baseline (303.145 us; speedup 1.0000x reference)
//
#include <hip/hip_runtime.h>
#include <stdint.h>

// ---------------------------------------------------------------------------
// Self_postrans: pe(60ch) -> QKV -> softmax(sqrt(384) Q^T K) -> P V
// B=8, N=2048, D=384. fp32 I/O; internal fp16 MFMA (fp32 accum).
// K1 (grid 512): pe 192-thread map + packed stores; W ushort4 staging.
// K2 (R17): split-K ACROSS BLOCKS. grid 512 = (b, qt, kh): each 256-thr
//     block (4 waves x 16 q-rows) does one K-half (32 tiles of 32 kv).
//     LDS 79872 B -> 2 blocks/CU = 2 waves/SIMD, blocks have INDEPENDENT
//     barriers -> co-resident blocks phase-shift (one drains DMA while the
//     other computes). R14's 8-wave single block was lockstep (R16 5th null).
//     Each block writes RAW partial O (kh0 -> d_out, kh1 -> ws PO1) + m/l
//     to ws ML. K3 merge kernel combines (online-softmax, exp2).
//     NOTE R15: full-K 4-wave blocks = 1 wave/SIMD (fixed 1024 q-waves);
//     split-K x2 is REQUIRED for 2 waves/SIMD.
//     NOTE R16: staggered staging regressed; V+K both staged at tile top.
//     NOTE R13: Q streaming regressed; Q hi+lo resident. R9: setprio null.
// ---------------------------------------------------------------------------

typedef unsigned short u16;
typedef unsigned int   u32;
using h16x8 = __attribute__((ext_vector_type(8))) _Float16;
using f32x4 = __attribute__((ext_vector_type(4))) float;

#define MF16(a,b,c) __builtin_amdgcn_mfma_f32_16x16x32_f16((a),(b),(c),0,0,0)

__device__ __forceinline__ u16 f2h_u(float x) { union { _Float16 h; u16 u; } v; v.h = (_Float16)x; return v.u; }
__device__ __forceinline__ float h2f(u16 u)   { union { _Float16 h; u16 u; } v; v.u = u; return (float)v.h; }

__device__ __forceinline__ float rmax16(float x) {
  x = fmaxf(x, __shfl_xor(x, 1, 16));
  x = fmaxf(x, __shfl_xor(x, 2, 16));
  x = fmaxf(x, __shfl_xor(x, 4, 16));
  x = fmaxf(x, __shfl_xor(x, 8, 16));
  return x;
}

__device__ __forceinline__ void glds16(const void* g, u16* l) {
  __builtin_amdgcn_global_load_lds((const __attribute__((address_space(1))) u32*)g,
                                   (__attribute__((address_space(3))) u32*)l, 16, 0, 0);
}

// ws byte offsets: fp16 tensors (12.58 MB each), then fp32 partials
#define QH_OFF 0u
#define QL_OFF 12582912u
#define KH_OFF 25165824u
#define VV_OFF 37748736u
#define PO1_OFF 50331648u   // float[8][384][2048] = 25.17 MB (kh=1 partial O)
#define ML_OFF  75497472u   // float m0/m1/l0/l1 [each 8][2048] = 262144 B

// sqrt(384) * log2(e): scores land in log2 units -> native v_exp_f32 (exp2)
#define SC 28.270933952f

// ---------------------------------------------------------------------------
// K1: grid 512 = (b = blk&7, nt = (blk>>3)&31, h = blk>>8). 256 thr, 2 blk/CU.
// ---------------------------------------------------------------------------
#define PH_E 0
#define PL_E 4608
#define WH_E 9216
#define WL_E 23040
#define TT_E 9216   // epilogue tiles overlay WH region (13824 elems)

__global__ __launch_bounds__(256, 2) void qkv_kernel(
    const float* __restrict__ pos,
    const float* __restrict__ Wq, const float* __restrict__ bq,
    const float* __restrict__ Wk, const float* __restrict__ bk,
    const float* __restrict__ Wv, const float* __restrict__ bv,
    u16* __restrict__ qh, u16* __restrict__ ql,
    u16* __restrict__ kh, u16* __restrict__ vv)
{
  const int tid = threadIdx.x;
  const int b = blockIdx.x & 7, nt = (blockIdx.x >> 3) & 31, h = blockIdx.x >> 8;
  const int w = tid >> 6, q15 = tid & 15, quad = (tid & 63) >> 4;

  __shared__ __align__(16) u16 sm[36864];  // 72 KB -> 2 blocks/CU

  // ---- pe: 192 threads = 3 coord x 64 n; packed u32 stores ----
  if (tid < 192) {
    const int coord = tid >> 6, n = tid & 63;
    const float p = pos[(b * 3 + coord) * 2048 + nt * 64 + n];
    const int base = n * 72 + coord * 20;
    u16 sh[10], ch[10], sl[10], cl[10];
#pragma unroll
    for (int j = 0; j < 10; ++j) {
      float x = p * (float)(1 << j);
      float s = __sinf(x), c = __cosf(x);
      sh[j] = f2h_u(s); sl[j] = f2h_u(s - h2f(sh[j]));
      ch[j] = f2h_u(c); cl[j] = f2h_u(c - h2f(ch[j]));
    }
#pragma unroll
    for (int j = 0; j < 10; j += 2) {
      *(u32*)&sm[PH_E + base + j]      = (u32)sh[j] | ((u32)sh[j + 1] << 16);
      *(u32*)&sm[PH_E + base + 10 + j] = (u32)ch[j] | ((u32)ch[j + 1] << 16);
      *(u32*)&sm[PL_E + base + j]      = (u32)sl[j] | ((u32)sl[j + 1] << 16);
      *(u32*)&sm[PL_E + base + 10 + j] = (u32)cl[j] | ((u32)cl[j + 1] << 16);
    }
  } else {
    const int n = tid - 192;
#pragma unroll
    for (int j = 0; j < 12; j += 2) {
      *(u32*)&sm[PH_E + n * 72 + 60 + j] = 0;
      *(u32*)&sm[PL_E + n * 72 + 60 + j] = 0;
    }
  }

  for (int mat = 0; mat < 3; ++mat) {
    const float* Wg = (mat == 0) ? Wq : ((mat == 1) ? Wk : Wv);
    const float* bg = (mat == 0) ? bq : ((mat == 1) ? bk : bv);
    __syncthreads();   // pe done (iter 0) / prior epilogue copies done

    // W staging: 15 float4/row, packed ushort4 hi/lo stores
    for (int i = tid; i < 2880; i += 256) {
      float4 v = *(const float4*)&Wg[(size_t)h * 11520 + (size_t)i * 4];
      int dd = i / 15, c4 = i % 15;
      int base = dd * 72 + c4 * 4;
      u16 h0 = f2h_u(v.x), h1 = f2h_u(v.y), h2 = f2h_u(v.z), h3 = f2h_u(v.w);
      ushort4 hv; hv.x = h0; hv.y = h1; hv.z = h2; hv.w = h3;
      ushort4 lv;
      lv.x = f2h_u(v.x - h2f(h0)); lv.y = f2h_u(v.y - h2f(h1));
      lv.z = f2h_u(v.z - h2f(h2)); lv.w = f2h_u(v.w - h2f(h3));
      *(ushort4*)&sm[WH_E + base] = hv;
      *(ushort4*)&sm[WL_E + base] = lv;
    }
    // zero pad columns 60..71
    for (int i = tid; i < 2304; i += 256) {
      int dd = i / 12, c = 60 + i % 12;
      sm[WH_E + dd * 72 + c] = 0;
      sm[WL_E + dd * 72 + c] = 0;
    }
    __syncthreads();

    f32x4 acc[3][4];
#pragma unroll
    for (int rf = 0; rf < 3; ++rf)
#pragma unroll
      for (int nf = 0; nf < 4; ++nf) acc[rf][nf] = (f32x4){0.f, 0.f, 0.f, 0.f};

#pragma unroll
    for (int ks = 0; ks < 2; ++ks) {
      const int co = ks * 32 + quad * 8;
      h16x8 bh[4], bl[4];
#pragma unroll
      for (int nf = 0; nf < 4; ++nf) {
        bh[nf] = *(const h16x8*)&sm[PH_E + (nf * 16 + q15) * 72 + co];
        bl[nf] = *(const h16x8*)&sm[PL_E + (nf * 16 + q15) * 72 + co];
      }
#pragma unroll
      for (int rf = 0; rf < 3; ++rf) {
        h16x8 ah = *(const h16x8*)&sm[WH_E + (w * 48 + rf * 16 + q15) * 72 + co];
        h16x8 al = *(const h16x8*)&sm[WL_E + (w * 48 + rf * 16 + q15) * 72 + co];
#pragma unroll
        for (int nf = 0; nf < 4; ++nf) {
          acc[rf][nf] = MF16(ah, bh[nf], acc[rf][nf]);
          acc[rf][nf] = MF16(ah, bl[nf], acc[rf][nf]);
          acc[rf][nf] = MF16(al, bh[nf], acc[rf][nf]);
        }
      }
    }

#pragma unroll
    for (int rf = 0; rf < 3; ++rf)
#pragma unroll
      for (int r = 0; r < 4; ++r) {
        float bi = bg[h * 192 + w * 48 + rf * 16 + quad * 4 + r];
#pragma unroll
        for (int nf = 0; nf < 4; ++nf) {
          float v = acc[rf][nf][r] + bi;
          acc[rf][nf][r] = (mat == 0) ? v * SC : v;
        }
      }
    __syncthreads();   // W reads done; TT may overwrite

    if (mat == 2) {
      // V: transposed tile [192 d][72 n] -> vv[b][d][n]
#pragma unroll
      for (int rf = 0; rf < 3; ++rf)
#pragma unroll
        for (int nf = 0; nf < 4; ++nf)
#pragma unroll
          for (int r = 0; r < 4; ++r)
            sm[TT_E + (w * 48 + rf * 16 + quad * 4 + r) * 72 + nf * 16 + q15] = f2h_u(acc[rf][nf][r]);
      __syncthreads();
      for (int c = tid; c < 1536; c += 256) {
        int d = c >> 3, k = c & 7;
        *(uint4*)&vv[((size_t)(b * 384 + h * 192 + d)) * 2048 + nt * 64 + k * 8] =
            *(const uint4*)&sm[TT_E + d * 72 + k * 8];
      }
    } else {
      const int npass = (mat == 0) ? 2 : 1;
      for (int pass = 0; pass < npass; ++pass) {
#pragma unroll
        for (int rf = 0; rf < 3; ++rf)
#pragma unroll
          for (int nf = 0; nf < 4; ++nf) {
            u16 e[4];
#pragma unroll
            for (int r = 0; r < 4; ++r) {
              float v = acc[rf][nf][r];
              e[r] = (pass == 0) ? f2h_u(v) : f2h_u(v - h2f(f2h_u(v)));
            }
            ushort4 pv; pv.x = e[0]; pv.y = e[1]; pv.z = e[2]; pv.w = e[3];
            *(ushort4*)&sm[TT_E + (nf * 16 + q15) * 200 + w * 48 + rf * 16 + quad * 4] = pv;
          }
        __syncthreads();
        u16* dst = (mat == 1) ? kh : ((pass == 0) ? qh : ql);
        for (int c = tid; c < 1536; c += 256) {
          int n = c / 24, k = c % 24;
          *(uint4*)&dst[((size_t)(b * 2048 + nt * 64 + n)) * 384 + h * 192 + k * 8] =
              *(const uint4*)&sm[TT_E + n * 200 + k * 8];
        }
        if (pass + 1 < npass) __syncthreads();
      }
    }
  }
}

// ---------------------------------------------------------------------------
// K2: flash attn, split-K across blocks. grid 512 = (b = blk&7,
// qt = (blk>>3)&31, kh = blk>>8). 256 thr = 4 waves x 16 q-rows.
// LDS (u16 elems, dynamic 79872 B -> 2 blocks/CU, independent barriers):
//   K buf f: f*12288          (32 rows x 768B, chunk^=(row&7))
//   V:       24576            (400 rows x 64B, chunk^=(d&3); 384..399 ones)
//   P wave w: 37376 + w*640   (16 x 40)
// Writes RAW partial O (kh0->out, kh1->po1) + m/l to ml. K3 merges.
// ---------------------------------------------------------------------------
#define KE2(f) ((f) * 12288)
#define VE2    24576
#define PE2    37376
#define K2_LDS_BYTES 79872

__global__ __launch_bounds__(256) __attribute__((amdgpu_waves_per_eu(2))) void attn_kernel(
    const u16* __restrict__ qhp, const u16* __restrict__ qlp,
    const u16* __restrict__ khp, const u16* __restrict__ vvp,
    float* __restrict__ po1, float* __restrict__ mlp,
    float* __restrict__ outp)
{
  extern __shared__ __align__(16) u16 smem[];
  const int tid = threadIdx.x;
  const int b = blockIdx.x & 7, qt = (blockIdx.x >> 3) & 31, kh2 = blockIdx.x >> 8;
  const int w = tid >> 6, lane = tid & 63, q15 = lane & 15, quad = lane >> 4;

  // K-staging source offsets within a 4-row (3072 B) group
  int kfo[6];
#pragma unroll
  for (int j = 0; j < 3; ++j)
#pragma unroll
    for (int p = 0; p < 2; ++p) {
      int sub = j * 1024 + lane * 16;
      int r0 = sub / 768;
      int cp = (sub - r0 * 768) >> 4;
      int rx = (4 * p + r0) & 7;                // == (global row) & 7
      int cl = (cp & ~7) | ((cp & 7) ^ rx);
      kfo[j * 2 + p] = r0 * 768 + cl * 16;
    }

  // Q hi/lo fragments in registers (fp16, SC folded)
  h16x8 qfh[12], qfl[12];
  {
    const size_t qr = ((size_t)(b * 2048 + qt * 64 + w * 16 + q15)) * 384;
#pragma unroll
    for (int ks = 0; ks < 12; ++ks) {
      qfh[ks] = *(const h16x8*)&qhp[qr + ks * 32 + quad * 8];
      qfl[ks] = *(const h16x8*)&qlp[qr + ks * 32 + quad * 8];
    }
  }

  // ones-row block: V rows 384..399 (row 384 = 1.0, rest = 0)
  for (int i = tid; i < 512; i += 256) {
    int rr = i >> 5, cc = i & 31;
    smem[VE2 + (384 + rr) * 32 + cc] = (rr == 0) ? (u16)0x3C00 : (u16)0;
  }

  const char* kbase = (const char*)(khp + ((size_t)b * 2048 + kh2 * 1024) * 384);

  // prologue: K tile 0 of this half -> buf 0 (6 DMA/wave)
#pragma unroll
  for (int t = 0; t < 6; ++t) {
    int g = w * 2 + t / 3;
    glds16(kbase + g * 3072 + kfo[(t % 3) * 2 + (g & 1)],
           &smem[KE2(0) + (w * 6 + t) * 512]);
  }
  __syncthreads();

  f32x4 o[25];   // o[24] = ones-row fragment: running softmax denominator
#pragma unroll
  for (int cf = 0; cf < 25; ++cf) o[cf] = (f32x4){0.f, 0.f, 0.f, 0.f};
  float mo[4];
#pragma unroll
  for (int r = 0; r < 4; ++r) mo[r] = -1e30f;

  for (int mt = 0; mt < 32; ++mt) {
    const int cur = mt & 1;

    // ---- stage V(mt) of this half: 384 rows x 64B, source-swizzled ----
    {
      const char* vt = (const char*)(vvp + (size_t)b * 384 * 2048 + kh2 * 1024 + mt * 32);
#pragma unroll
      for (int t = 0; t < 6; ++t) {
        int i = w * 6 + t;
        int d = i * 16 + (lane >> 2), s = lane & 3;
        glds16(vt + (size_t)d * 4096 + ((s ^ (d & 3)) * 16), &smem[VE2 + i * 512]);
      }
    }
    // ---- stage K(mt+1) -> other buffer ----
    {
      const char* kt = kbase + ((mt + 1) & 31) * 32 * 768;
#pragma unroll
      for (int t = 0; t < 6; ++t) {
        int g = w * 2 + t / 3;
        glds16(kt + g * 3072 + kfo[(t % 3) * 2 + (g & 1)],
               &smem[KE2(cur ^ 1) + (w * 6 + t) * 512]);
      }
    }

    // ---- S phase: separate hi/lo accumulators (4 MFMA chains) ----
    f32x4 sa[2], sb[2];
#pragma unroll
    for (int cf = 0; cf < 2; ++cf) { sa[cf] = (f32x4){0.f,0.f,0.f,0.f}; sb[cf] = (f32x4){0.f,0.f,0.f,0.f}; }
#pragma unroll
    for (int ks = 0; ks < 12; ++ks) {
#pragma unroll
      for (int cf = 0; cf < 2; ++cf) {
        const int row = cf * 16 + q15;
        const int c3 = (((ks & 1) * 4) | quad) ^ (q15 & 7);
        h16x8 bk = *(const h16x8*)&smem[KE2(cur) + row * 384 + ((ks >> 1) * 8 + c3) * 8];
        sa[cf] = MF16(qfh[ks], bk, sa[cf]);
        sb[cf] = MF16(qfl[ks], bk, sb[cf]);
      }
    }
#pragma unroll
    for (int cf = 0; cf < 2; ++cf) sa[cf] += sb[cf];

    // ---- online softmax (rows = quad*4+r; reduce over q15 x cf), exp2 ----
    float al[4], p0[4], p1[4];
#pragma unroll
    for (int r = 0; r < 4; ++r) {
      float mx = rmax16(fmaxf(sa[0][r], sa[1][r]));
      float mn = fmaxf(mo[r], mx);
      al[r] = exp2f(mo[r] - mn);
      mo[r] = mn;
      p0[r] = exp2f(sa[0][r] - mn);
      p1[r] = exp2f(sa[1][r] - mn);
    }
    // P -> LDS (wave-private, C-layout write / A-layout read)
#pragma unroll
    for (int r = 0; r < 4; ++r) {
      smem[PE2 + w * 640 + (quad * 4 + r) * 40 +      q15] = f2h_u(p0[r]);
      smem[PE2 + w * 640 + (quad * 4 + r) * 40 + 16 + q15] = f2h_u(p1[r]);
    }
    // O rescale (incl. o[24] = denominator)
#pragma unroll
    for (int cf = 0; cf < 25; ++cf)
#pragma unroll
      for (int r = 0; r < 4; ++r) o[cf][r] *= al[r];

    __syncthreads();   // B: V(mt) + K(mt+1) DMA drained (4 waves only)

    // ---- PV (cf=24 hits ones-row block -> sum(P) at q15==0) ----
    h16x8 pa = *(const h16x8*)&smem[PE2 + w * 640 + q15 * 40 + quad * 8];
#pragma unroll
    for (int cf = 0; cf < 25; ++cf) {
      const int d = cf * 16 + q15;
      h16x8 vb = *(const h16x8*)&smem[VE2 + d * 32 + ((quad ^ (d & 3)) * 8)];
      o[cf] = MF16(pa, vb, o[cf]);
    }

    __syncthreads();   // A: PV reads done -> next tile may overwrite V
  }

  // ---- epilogue: write RAW partial O + m/l (merge kernel combines) ----
  float* od = (kh2 == 0) ? outp : po1;
#pragma unroll
  for (int cf = 0; cf < 24; ++cf) {
    const int d = cf * 16 + q15;
    float4 st;
    st.x = o[cf][0]; st.y = o[cf][1]; st.z = o[cf][2]; st.w = o[cf][3];
    *(float4*)&od[((size_t)(b * 384 + d)) * 2048 + qt * 64 + w * 16 + quad * 4] = st;
  }
  if (q15 == 0) {
#pragma unroll
    for (int r = 0; r < 4; ++r) {
      const int n = qt * 64 + w * 16 + quad * 4 + r;
      mlp[(size_t)(kh2 * 8 + b) * 2048 + n] = mo[r];            // m[kh]
      mlp[(size_t)((2 + kh2) * 8 + b) * 2048 + n] = o[24][r];   // l[kh]
    }
  }
}

// ---------------------------------------------------------------------------
// K3: merge the two K-half partials (online-softmax combine, exp2 units).
// out = (O0*e0 + O1*e1) / (l0*e0 + l1*e1), e_k = exp2(m_k - max(m0,m1)).
// ---------------------------------------------------------------------------
__global__ __launch_bounds__(256) void merge_kernel(
    const float* __restrict__ po1, const float* __restrict__ mlp,
    float* __restrict__ outp)
{
  const size_t total = (size_t)8 * 384 * 512;   // float4 count
  const float4* mv = (const float4*)mlp;
  for (size_t i = (size_t)blockIdx.x * 256 + threadIdx.x; i < total;
       i += (size_t)gridDim.x * 256) {
    const int n4 = (int)(i & 511);
    const size_t bd = i >> 9;
    const int b = (int)(bd / 384);
    const int mbase = b * 512 + n4;
    float4 m0 = mv[0 * 4096 + mbase];
    float4 m1 = mv[1 * 4096 + mbase];
    float4 l0 = mv[2 * 4096 + mbase];
    float4 l1 = mv[3 * 4096 + mbase];
    float4 o0 = ((const float4*)outp)[i];
    float4 o1 = ((const float4*)po1)[i];
    float4 r;
    {
      float mn = fmaxf(m0.x, m1.x), e0 = exp2f(m0.x - mn), e1 = exp2f(m1.x - mn);
      r.x = (o0.x * e0 + o1.x * e1) / (l0.x * e0 + l1.x * e1);
    }
    {
      float mn = fmaxf(m0.y, m1.y), e0 = exp2f(m0.y - mn), e1 = exp2f(m1.y - mn);
      r.y = (o0.y * e0 + o1.y * e1) / (l0.y * e0 + l1.y * e1);
    }
    {
      float mn = fmaxf(m0.z, m1.z), e0 = exp2f(m0.z - mn), e1 = exp2f(m1.z - mn);
      r.z = (o0.z * e0 + o1.z * e1) / (l0.z * e0 + l1.z * e1);
    }
    {
      float mn = fmaxf(m0.w, m1.w), e0 = exp2f(m0.w - mn), e1 = exp2f(m1.w - mn);
      r.w = (o0.w * e0 + o1.w * e1) / (l0.w * e0 + l1.w * e1);
    }
    ((float4*)outp)[i] = r;
  }
}

extern "C" void kernel_launch(void* const* d_in, const int* in_sizes, int n_in,
                              void* d_out, int out_size, void* d_ws, size_t ws_size,
                              hipStream_t stream) {
  const float* pos = (const float*)d_in[0];
  const float* Wq  = (const float*)d_in[1];
  const float* bq  = (const float*)d_in[2];
  const float* Wk  = (const float*)d_in[3];
  const float* bk  = (const float*)d_in[4];
  const float* Wv  = (const float*)d_in[5];
  const float* bv  = (const float*)d_in[6];

  char* ws = (char*)d_ws;
  u16* qh  = (u16*)(ws + QH_OFF);
  u16* ql  = (u16*)(ws + QL_OFF);
  u16* kh  = (u16*)(ws + KH_OFF);
  u16* vv  = (u16*)(ws + VV_OFF);
  float* po1 = (float*)(ws + PO1_OFF);
  float* mlp = (float*)(ws + ML_OFF);

  qkv_kernel<<<512, 256, 0, stream>>>(pos, Wq, bq, Wk, bk, Wv, bv, qh, ql, kh, vv);
  attn_kernel<<<512, 256, K2_LDS_BYTES, stream>>>(qh, ql, kh, vv, po1, mlp, (float*)d_out);
  merge_kernel<<<2048, 256, 0, stream>>>(po1, mlp, (float*)d_out);
}

// Round 18
// 262.927 us; speedup vs baseline: 1.1530x; 1.1530x over previous
//
#include <hip/hip_runtime.h>
#include <stdint.h>

// ---------------------------------------------------------------------------
// Self_postrans: pe(60ch) -> QKV -> softmax(sqrt(384) Q^T K) -> P V
// B=8, N=2048, D=384. fp32 I/O; internal fp16 MFMA (fp32 accum).
// R18 = R14 exact (session best, 263.4us): K1 vectorized; K2 in-block
// split-K with ones-row denominator.
// K1 (grid 512 = b x nt x h-half): pe via 192-thread (coord x n) map,
//     packed u32 LDS stores; W fp16 hi/lo ushort4 staging; ushort4 epilogue.
//     Outputs: Q hi+lo (SC incl log2e), K fp16, V fp16 [d][n].
// K2: grid 256 x 512 thr, dynamic LDS 159744 B, 1 block/CU = 2 waves/SIMD;
//     in-block split-K (2 kh-halves x 4 q-waves of 16 rows); K dbuf + V via
//     swizzled global_load_lds; ONES-ROW block (PV 25th fragment = softmax
//     denominator by MFMA, no rsum16); in-LDS merge at block end.
// PLATEAU LEDGER (structural attempts at the ~60% stall, all null/negative):
//     R9 setprio (lockstep), R13 Q-stream (vmcnt FIFO), R15 full-K 4-wave
//     (1 wave/SIMD), R16 staggered staging (short PV cover + spill),
//     R17 cross-block split-K + merge (2 waves/SIMD + independent barriers,
//     attn 210 > 187: overlap gain < 2x partial-write cost). The per-tile
//     wait is intrinsic: DMA L2 latency + serial softmax + b128 LDS floor
//     at fixed 2 waves/SIMD.
// ---------------------------------------------------------------------------

typedef unsigned short u16;
typedef unsigned int   u32;
using h16x8 = __attribute__((ext_vector_type(8))) _Float16;
using f32x4 = __attribute__((ext_vector_type(4))) float;

#define MF16(a,b,c) __builtin_amdgcn_mfma_f32_16x16x32_f16((a),(b),(c),0,0,0)

__device__ __forceinline__ u16 f2h_u(float x) { union { _Float16 h; u16 u; } v; v.h = (_Float16)x; return v.u; }
__device__ __forceinline__ float h2f(u16 u)   { union { _Float16 h; u16 u; } v; v.u = u; return (float)v.h; }

__device__ __forceinline__ float rmax16(float x) {
  x = fmaxf(x, __shfl_xor(x, 1, 16));
  x = fmaxf(x, __shfl_xor(x, 2, 16));
  x = fmaxf(x, __shfl_xor(x, 4, 16));
  x = fmaxf(x, __shfl_xor(x, 8, 16));
  return x;
}

__device__ __forceinline__ void glds16(const void* g, u16* l) {
  __builtin_amdgcn_global_load_lds((const __attribute__((address_space(1))) u32*)g,
                                   (__attribute__((address_space(3))) u32*)l, 16, 0, 0);
}

// ws byte offsets (fp16 tensors, 12.58 MB each)
#define QH_OFF 0u
#define QL_OFF 12582912u
#define KH_OFF 25165824u
#define VV_OFF 37748736u

// sqrt(384) * log2(e): scores land in log2 units -> native v_exp_f32 (exp2)
#define SC 28.270933952f

// ---------------------------------------------------------------------------
// K1: grid 512 = (b = blk&7, nt = (blk>>3)&31, h = blk>>8). 256 thr, 2 blk/CU.
// ---------------------------------------------------------------------------
#define PH_E 0
#define PL_E 4608
#define WH_E 9216
#define WL_E 23040
#define TT_E 9216   // epilogue tiles overlay WH region (13824 elems)

__global__ __launch_bounds__(256, 2) void qkv_kernel(
    const float* __restrict__ pos,
    const float* __restrict__ Wq, const float* __restrict__ bq,
    const float* __restrict__ Wk, const float* __restrict__ bk,
    const float* __restrict__ Wv, const float* __restrict__ bv,
    u16* __restrict__ qh, u16* __restrict__ ql,
    u16* __restrict__ kh, u16* __restrict__ vv)
{
  const int tid = threadIdx.x;
  const int b = blockIdx.x & 7, nt = (blockIdx.x >> 3) & 31, h = blockIdx.x >> 8;
  const int w = tid >> 6, q15 = tid & 15, quad = (tid & 63) >> 4;

  __shared__ __align__(16) u16 sm[36864];  // 72 KB -> 2 blocks/CU

  // ---- pe: 192 threads = 3 coord x 64 n; 1 pos load + 10 sin + 10 cos each,
  //      hi/lo planes via packed u32 stores; threads 192..255 zero pad cols ----
  if (tid < 192) {
    const int coord = tid >> 6, n = tid & 63;
    const float p = pos[(b * 3 + coord) * 2048 + nt * 64 + n];
    const int base = n * 72 + coord * 20;
    u16 sh[10], ch[10], sl[10], cl[10];
#pragma unroll
    for (int j = 0; j < 10; ++j) {
      float x = p * (float)(1 << j);
      float s = __sinf(x), c = __cosf(x);
      sh[j] = f2h_u(s); sl[j] = f2h_u(s - h2f(sh[j]));
      ch[j] = f2h_u(c); cl[j] = f2h_u(c - h2f(ch[j]));
    }
#pragma unroll
    for (int j = 0; j < 10; j += 2) {
      *(u32*)&sm[PH_E + base + j]      = (u32)sh[j] | ((u32)sh[j + 1] << 16);
      *(u32*)&sm[PH_E + base + 10 + j] = (u32)ch[j] | ((u32)ch[j + 1] << 16);
      *(u32*)&sm[PL_E + base + j]      = (u32)sl[j] | ((u32)sl[j + 1] << 16);
      *(u32*)&sm[PL_E + base + 10 + j] = (u32)cl[j] | ((u32)cl[j + 1] << 16);
    }
  } else {
    const int n = tid - 192;
#pragma unroll
    for (int j = 0; j < 12; j += 2) {
      *(u32*)&sm[PH_E + n * 72 + 60 + j] = 0;
      *(u32*)&sm[PL_E + n * 72 + 60 + j] = 0;
    }
  }

  for (int mat = 0; mat < 3; ++mat) {
    const float* Wg = (mat == 0) ? Wq : ((mat == 1) ? Wk : Wv);
    const float* bg = (mat == 0) ? bq : ((mat == 1) ? bk : bv);
    __syncthreads();   // pe done (iter 0) / prior epilogue copies done

    // W staging: 15 float4/row, packed ushort4 hi/lo stores (2 per float4)
    for (int i = tid; i < 2880; i += 256) {
      float4 v = *(const float4*)&Wg[(size_t)h * 11520 + (size_t)i * 4];
      int dd = i / 15, c4 = i % 15;
      int base = dd * 72 + c4 * 4;
      u16 h0 = f2h_u(v.x), h1 = f2h_u(v.y), h2 = f2h_u(v.z), h3 = f2h_u(v.w);
      ushort4 hv; hv.x = h0; hv.y = h1; hv.z = h2; hv.w = h3;
      ushort4 lv;
      lv.x = f2h_u(v.x - h2f(h0)); lv.y = f2h_u(v.y - h2f(h1));
      lv.z = f2h_u(v.z - h2f(h2)); lv.w = f2h_u(v.w - h2f(h3));
      *(ushort4*)&sm[WH_E + base] = hv;
      *(ushort4*)&sm[WL_E + base] = lv;
    }
    // zero pad columns 60..71
    for (int i = tid; i < 2304; i += 256) {
      int dd = i / 12, c = 60 + i % 12;
      sm[WH_E + dd * 72 + c] = 0;
      sm[WL_E + dd * 72 + c] = 0;
    }
    __syncthreads();

    f32x4 acc[3][4];
#pragma unroll
    for (int rf = 0; rf < 3; ++rf)
#pragma unroll
      for (int nf = 0; nf < 4; ++nf) acc[rf][nf] = (f32x4){0.f, 0.f, 0.f, 0.f};

#pragma unroll
    for (int ks = 0; ks < 2; ++ks) {
      const int co = ks * 32 + quad * 8;
      h16x8 bh[4], bl[4];
#pragma unroll
      for (int nf = 0; nf < 4; ++nf) {
        bh[nf] = *(const h16x8*)&sm[PH_E + (nf * 16 + q15) * 72 + co];
        bl[nf] = *(const h16x8*)&sm[PL_E + (nf * 16 + q15) * 72 + co];
      }
#pragma unroll
      for (int rf = 0; rf < 3; ++rf) {
        h16x8 ah = *(const h16x8*)&sm[WH_E + (w * 48 + rf * 16 + q15) * 72 + co];
        h16x8 al = *(const h16x8*)&sm[WL_E + (w * 48 + rf * 16 + q15) * 72 + co];
#pragma unroll
        for (int nf = 0; nf < 4; ++nf) {
          acc[rf][nf] = MF16(ah, bh[nf], acc[rf][nf]);
          acc[rf][nf] = MF16(ah, bl[nf], acc[rf][nf]);
          acc[rf][nf] = MF16(al, bh[nf], acc[rf][nf]);
        }
      }
    }

#pragma unroll
    for (int rf = 0; rf < 3; ++rf)
#pragma unroll
      for (int r = 0; r < 4; ++r) {
        float bi = bg[h * 192 + w * 48 + rf * 16 + quad * 4 + r];
#pragma unroll
        for (int nf = 0; nf < 4; ++nf) {
          float v = acc[rf][nf][r] + bi;
          acc[rf][nf][r] = (mat == 0) ? v * SC : v;
        }
      }
    __syncthreads();   // W reads done; TT may overwrite

    if (mat == 2) {
      // V: transposed tile [192 d][72 n] -> vv[b][d][n]
#pragma unroll
      for (int rf = 0; rf < 3; ++rf)
#pragma unroll
        for (int nf = 0; nf < 4; ++nf)
#pragma unroll
          for (int r = 0; r < 4; ++r)
            sm[TT_E + (w * 48 + rf * 16 + quad * 4 + r) * 72 + nf * 16 + q15] = f2h_u(acc[rf][nf][r]);
      __syncthreads();
      for (int c = tid; c < 1536; c += 256) {
        int d = c >> 3, k = c & 7;
        *(uint4*)&vv[((size_t)(b * 384 + h * 192 + d)) * 2048 + nt * 64 + k * 8] =
            *(const uint4*)&sm[TT_E + d * 72 + k * 8];
      }
    } else {
      const int npass = (mat == 0) ? 2 : 1;
      for (int pass = 0; pass < npass; ++pass) {
#pragma unroll
        for (int rf = 0; rf < 3; ++rf)
#pragma unroll
          for (int nf = 0; nf < 4; ++nf) {
            u16 e[4];
#pragma unroll
            for (int r = 0; r < 4; ++r) {
              float v = acc[rf][nf][r];
              e[r] = (pass == 0) ? f2h_u(v) : f2h_u(v - h2f(f2h_u(v)));
            }
            ushort4 pv; pv.x = e[0]; pv.y = e[1]; pv.z = e[2]; pv.w = e[3];
            *(ushort4*)&sm[TT_E + (nf * 16 + q15) * 200 + w * 48 + rf * 16 + quad * 4] = pv;
          }
        __syncthreads();
        u16* dst = (mat == 1) ? kh : ((pass == 0) ? qh : ql);
        for (int c = tid; c < 1536; c += 256) {
          int n = c / 24, k = c % 24;
          *(uint4*)&dst[((size_t)(b * 2048 + nt * 64 + n)) * 384 + h * 192 + k * 8] =
              *(const uint4*)&sm[TT_E + n * 200 + k * 8];
        }
        if (pass + 1 < npass) __syncthreads();
      }
    }
  }
}

// ---------------------------------------------------------------------------
// K2: flash attn, in-block split-K. grid 256 = (b = blk&7, qt = blk>>3),
// 512 thr = 8 waves: kh = w>>2 (K-half), qw = w&3 (16-q-row group).
// LDS (u16 elems, dynamic 159744 B):
//   K half kh buf f: kh*24576 + f*12288   (32 rows x 768B, chunk^=(row&7))
//   V half kh:       49152 + kh*12800     (400 rows x 64B, chunk^=(d&3);
//                                          rows 384..399 = ones-row block)
//   P wave w:        74752 + w*640        (16 x 40)
// Epilogue overlay (f32): M[384][68] + m[64] + l[64].
// ---------------------------------------------------------------------------
#define KEH(kh,f) ((kh) * 24576 + (f) * 12288)
#define VEH(kh)   (49152 + (kh) * 12800)
#define PEH       74752
#define K2_LDS_BYTES 159744

__global__ __launch_bounds__(512) __attribute__((amdgpu_waves_per_eu(2))) void attn_kernel(
    const u16* __restrict__ qhp, const u16* __restrict__ qlp,
    const u16* __restrict__ khp, const u16* __restrict__ vvp,
    float* __restrict__ outp)
{
  extern __shared__ __align__(16) u16 smem[];
  const int tid = threadIdx.x;
  const int b = blockIdx.x & 7, qt = blockIdx.x >> 3;
  const int w = tid >> 6, lane = tid & 63, q15 = lane & 15, quad = lane >> 4;
  const int kh2 = w >> 2, qw = w & 3;

  // K-staging source offsets within a 4-row (3072 B) group
  int kfo[6];
#pragma unroll
  for (int j = 0; j < 3; ++j)
#pragma unroll
    for (int p = 0; p < 2; ++p) {
      int sub = j * 1024 + lane * 16;
      int r0 = sub / 768;
      int cp = (sub - r0 * 768) >> 4;
      int rx = (4 * p + r0) & 7;                // == (global row) & 7
      int cl = (cp & ~7) | ((cp & 7) ^ rx);
      kfo[j * 2 + p] = r0 * 768 + cl * 16;
    }

  // Q hi/lo fragments in registers (fp16, SC folded)
  h16x8 qfh[12], qfl[12];
  {
    const size_t qr = ((size_t)(b * 2048 + qt * 64 + qw * 16 + q15)) * 384;
#pragma unroll
    for (int ks = 0; ks < 12; ++ks) {
      qfh[ks] = *(const h16x8*)&qhp[qr + ks * 32 + quad * 8];
      qfl[ks] = *(const h16x8*)&qlp[qr + ks * 32 + quad * 8];
    }
  }

  // ones-row block: V rows 384..399 of each half (row 384 = 1.0, rest = 0)
  for (int i = tid; i < 1024; i += 512) {
    int half = i >> 9, rr = (i >> 5) & 15, cc = i & 31;
    smem[VEH(half) + (384 + rr) * 32 + cc] = (rr == 0) ? (u16)0x3C00 : (u16)0;
  }

  const char* kbase = (const char*)(khp + ((size_t)b * 2048 + kh2 * 1024) * 384);

  // prologue: K tile 0 of this half -> buf 0 (6 DMA/wave)
#pragma unroll
  for (int t = 0; t < 6; ++t) {
    int g = qw * 2 + t / 3;
    glds16(kbase + g * 3072 + kfo[(t % 3) * 2 + (g & 1)],
           &smem[KEH(kh2, 0) + (qw * 6 + t) * 512]);
  }
  __syncthreads();

  f32x4 o[25];   // o[24] = ones-row fragment: running softmax denominator
#pragma unroll
  for (int cf = 0; cf < 25; ++cf) o[cf] = (f32x4){0.f, 0.f, 0.f, 0.f};
  float mo[4];
#pragma unroll
  for (int r = 0; r < 4; ++r) mo[r] = -1e30f;

  for (int mt = 0; mt < 32; ++mt) {
    const int cur = mt & 1;

    // ---- stage V(mt) of this half: 384 rows x 64B, source-swizzled (6 DMA) ----
    {
      const char* vt = (const char*)(vvp + (size_t)b * 384 * 2048 + kh2 * 1024 + mt * 32);
#pragma unroll
      for (int t = 0; t < 6; ++t) {
        int i = qw * 6 + t;
        int d = i * 16 + (lane >> 2), s = lane & 3;
        glds16(vt + (size_t)d * 4096 + ((s ^ (d & 3)) * 16), &smem[VEH(kh2) + i * 512]);
      }
    }
    // ---- stage K(mt+1) -> other buffer (6 DMA) ----
    {
      const char* kt = kbase + ((mt + 1) & 31) * 32 * 768;
#pragma unroll
      for (int t = 0; t < 6; ++t) {
        int g = qw * 2 + t / 3;
        glds16(kt + g * 3072 + kfo[(t % 3) * 2 + (g & 1)],
               &smem[KEH(kh2, cur ^ 1) + (qw * 6 + t) * 512]);
      }
    }

    // ---- S phase: separate hi/lo accumulators (4 MFMA chains) ----
    f32x4 sa[2], sb[2];
#pragma unroll
    for (int cf = 0; cf < 2; ++cf) { sa[cf] = (f32x4){0.f,0.f,0.f,0.f}; sb[cf] = (f32x4){0.f,0.f,0.f,0.f}; }
#pragma unroll
    for (int ks = 0; ks < 12; ++ks) {
#pragma unroll
      for (int cf = 0; cf < 2; ++cf) {
        const int row = cf * 16 + q15;
        const int c3 = (((ks & 1) * 4) | quad) ^ (q15 & 7);
        h16x8 bk = *(const h16x8*)&smem[KEH(kh2, cur) + row * 384 + ((ks >> 1) * 8 + c3) * 8];
        sa[cf] = MF16(qfh[ks], bk, sa[cf]);
        sb[cf] = MF16(qfl[ks], bk, sb[cf]);
      }
    }
#pragma unroll
    for (int cf = 0; cf < 2; ++cf) sa[cf] += sb[cf];

    // ---- online softmax (rows = quad*4+r; reduce over q15 x cf), exp2 ----
    // denominator handled by ones-row PV fragment o[24] (no rsum16 needed)
    float al[4], p0[4], p1[4];
#pragma unroll
    for (int r = 0; r < 4; ++r) {
      float mx = rmax16(fmaxf(sa[0][r], sa[1][r]));
      float mn = fmaxf(mo[r], mx);
      al[r] = exp2f(mo[r] - mn);
      mo[r] = mn;
      p0[r] = exp2f(sa[0][r] - mn);
      p1[r] = exp2f(sa[1][r] - mn);
    }
    // P -> LDS (wave-private, C-layout write / A-layout read)
#pragma unroll
    for (int r = 0; r < 4; ++r) {
      smem[PEH + w * 640 + (quad * 4 + r) * 40 +      q15] = f2h_u(p0[r]);
      smem[PEH + w * 640 + (quad * 4 + r) * 40 + 16 + q15] = f2h_u(p1[r]);
    }
    // O rescale (incl. o[24] = denominator: l' = l*al + sum(P) via PV)
#pragma unroll
    for (int cf = 0; cf < 25; ++cf)
#pragma unroll
      for (int r = 0; r < 4; ++r) o[cf][r] *= al[r];

    __syncthreads();   // B: V(mt) + K(mt+1) DMA drained across the half

    // ---- PV (cf=24 hits ones-row block -> accumulates sum(P) at q15==0) ----
    h16x8 pa = *(const h16x8*)&smem[PEH + w * 640 + q15 * 40 + quad * 8];
#pragma unroll
    for (int cf = 0; cf < 25; ++cf) {
      const int d = cf * 16 + q15;
      h16x8 vb = *(const h16x8*)&smem[VEH(kh2) + d * 32 + ((quad ^ (d & 3)) * 8)];
      o[cf] = MF16(pa, vb, o[cf]);
    }

    __syncthreads();   // A: PV reads done -> next tile may overwrite V
  }

  // ---- epilogue: in-LDS merge of the two kh halves (exp2 units) ----
  float* M  = (float*)smem;      // [384][68] f32 raw partial O of half 1
  float* Lm = M + 26112;         // [64] running max of half 1
  float* Ll = M + 26176;         // [64] denominator of half 1

  if (kh2 == 1) {
#pragma unroll
    for (int cf = 0; cf < 24; ++cf) {
      float4 st; st.x = o[cf][0]; st.y = o[cf][1]; st.z = o[cf][2]; st.w = o[cf][3];
      *(float4*)&M[(size_t)(cf * 16 + q15) * 68 + qw * 16 + quad * 4] = st;
    }
    if (q15 == 0) {
#pragma unroll
      for (int r = 0; r < 4; ++r) {
        Lm[qw * 16 + quad * 4 + r] = mo[r];
        Ll[qw * 16 + quad * 4 + r] = o[24][r];   // denom lives at q15==0
      }
    }
  }
  __syncthreads();

  if (kh2 == 0) {
    float eA[4], eB[4], inv[4];
#pragma unroll
    for (int r = 0; r < 4; ++r) {
      const int n = qw * 16 + quad * 4 + r;
      float lA = __shfl(o[24][r], 0, 16);        // broadcast denom from q15==0
      float mB = Lm[n], lB = Ll[n];
      float mn = fmaxf(mo[r], mB);
      eA[r] = exp2f(mo[r] - mn);
      eB[r] = exp2f(mB - mn);
      inv[r] = 1.0f / (lA * eA[r] + lB * eB[r]);
    }
#pragma unroll
    for (int cf = 0; cf < 24; ++cf) {
      const int d = cf * 16 + q15;
      float4 ob = *(const float4*)&M[(size_t)d * 68 + qw * 16 + quad * 4];
      float4 st;
      st.x = (o[cf][0] * eA[0] + ob.x * eB[0]) * inv[0];
      st.y = (o[cf][1] * eA[1] + ob.y * eB[1]) * inv[1];
      st.z = (o[cf][2] * eA[2] + ob.z * eB[2]) * inv[2];
      st.w = (o[cf][3] * eA[3] + ob.w * eB[3]) * inv[3];
      *(float4*)&outp[((size_t)(b * 384 + d)) * 2048 + qt * 64 + qw * 16 + quad * 4] = st;
    }
  }
}

extern "C" void kernel_launch(void* const* d_in, const int* in_sizes, int n_in,
                              void* d_out, int out_size, void* d_ws, size_t ws_size,
                              hipStream_t stream) {
  const float* pos = (const float*)d_in[0];
  const float* Wq  = (const float*)d_in[1];
  const float* bq  = (const float*)d_in[2];
  const float* Wk  = (const float*)d_in[3];
  const float* bk  = (const float*)d_in[4];
  const float* Wv  = (const float*)d_in[5];
  const float* bv  = (const float*)d_in[6];

  char* ws = (char*)d_ws;
  u16* qh = (u16*)(ws + QH_OFF);
  u16* ql = (u16*)(ws + QL_OFF);
  u16* kh = (u16*)(ws + KH_OFF);
  u16* vv = (u16*)(ws + VV_OFF);

  qkv_kernel<<<512, 256, 0, stream>>>(pos, Wq, bq, Wk, bk, Wv, bv, qh, ql, kh, vv);
  attn_kernel<<<256, 512, K2_LDS_BYTES, stream>>>(qh, ql, kh, vv, (float*)d_out);
}